// Round 1
// baseline (843.271 us; speedup 1.0000x reference)
//
#include <hip/hip_runtime.h>
#include <cstdint>

#define T_TOK 8192
#define D_DIM 1024
#define E_EXP 8
#define F_DIM 3584
#define NROW  (2 * T_TOK)   // total (token, expert-slot) assignment rows

typedef __attribute__((ext_vector_type(8))) __bf16 bf16x8;
typedef __attribute__((ext_vector_type(4))) __bf16 bf16x4;
typedef __attribute__((ext_vector_type(4))) float f32x4;

// -------- async global->LDS (16B per lane; LDS dest = wave-uniform base + lane*16) --------
__device__ __forceinline__ void gload16(const void* g, void* l) {
    __builtin_amdgcn_global_load_lds(
        (const __attribute__((address_space(1))) void*)(g),
        (__attribute__((address_space(3))) void*)(l),
        16, 0, 0);
}

// -------- fp32 -> bf16 conversion (vectorized, 4 elems/thread) --------
__global__ void cvt_kernel(const float* __restrict__ in, __bf16* __restrict__ out, long n) {
    long i = ((long)blockIdx.x * blockDim.x + threadIdx.x) * 4;
    if (i >= n) return;
    const float4 f = *(const float4*)(in + i);
    bf16x4 o;
    o[0] = (__bf16)f.x; o[1] = (__bf16)f.y; o[2] = (__bf16)f.z; o[3] = (__bf16)f.w;
    *(bf16x4*)(out + i) = o;
}

// -------- routing: top-2 of 8 logits, renormalized softmax weights --------
__global__ void route_kernel(const float* __restrict__ rl, int* cnt,
                             int* __restrict__ eidx, float* __restrict__ ewgt) {
    int t = blockIdx.x * blockDim.x + threadIdx.x;
    if (t >= T_TOK) return;
    float l[8];
#pragma unroll
    for (int e = 0; e < 8; ++e) l[e] = rl[t * 8 + e];
    int i0 = 0; float v0 = l[0];
    int i1 = -1; float v1 = -1e30f;
#pragma unroll
    for (int e = 1; e < 8; ++e) {
        if (l[e] > v0) { v1 = v0; i1 = i0; v0 = l[e]; i0 = e; }
        else if (l[e] > v1) { v1 = l[e]; i1 = e; }
    }
    // top-2 softmax renorm: w_second = 1/(1+exp(l0-l1)), w_first = 1 - w_second
    float wsec = 1.f / (1.f + __expf(v0 - v1));
    eidx[2 * t] = i0; eidx[2 * t + 1] = i1;
    ewgt[2 * t] = 1.f - wsec; ewgt[2 * t + 1] = wsec;
    atomicAdd(&cnt[i0], 1); atomicAdd(&cnt[i1], 1);
}

__global__ void scan_kernel(const int* __restrict__ cnt, int* __restrict__ offs) {
    if (threadIdx.x == 0) {
        int a = 0;
        for (int e = 0; e < E_EXP; ++e) { offs[e] = a; a += cnt[e]; }
        offs[E_EXP] = a;
    }
}

__global__ void assign_kernel(const int* __restrict__ eidx, const float* __restrict__ ewgt,
                              const int* __restrict__ offs, int* cnt2,
                              int* __restrict__ tok, float* __restrict__ wgt) {
    int t = blockIdx.x * blockDim.x + threadIdx.x;
    if (t >= T_TOK) return;
#pragma unroll
    for (int s = 0; s < 2; ++s) {
        int e = eidx[2 * t + s];
        int pos = atomicAdd(&cnt2[e], 1);
        int row = offs[e] + pos;
        tok[row] = t;
        wgt[row] = ewgt[2 * t + s];
    }
}

// =========================================================================
// GEMM1: for each expert e, gathered rows of xb [rows, D] x {w1,w3}[e]^T [F, D]
//        -> h[row, f] = silu(gate) * up   (bf16)
// 128x128 tile, BK=32, 4 waves (2x2), 4x4 frags of 16x16x32 per wave.
// =========================================================================
__global__ __launch_bounds__(256, 2)
void gemm1_kernel(const __bf16* __restrict__ xb,
                  const __bf16* __restrict__ w1b,
                  const __bf16* __restrict__ w3b,
                  const int* __restrict__ tok_of_row,
                  const int* __restrict__ offs,
                  __bf16* __restrict__ h) {
    const int e  = blockIdx.z;
    const int mt = blockIdx.y;
    const int nt = blockIdx.x;
    const int row0 = offs[e];
    const int rows = offs[e + 1] - row0;
    if (mt * 128 >= rows) return;

    __shared__ __align__(16) __bf16 As[2][128 * 32];
    __shared__ __align__(16) __bf16 B1s[2][128 * 32];
    __shared__ __align__(16) __bf16 B3s[2][128 * 32];

    const int tid = threadIdx.x;
    const int wave = tid >> 6, lane = tid & 63;
    const int wm = wave >> 1, wn = wave & 1;
    const int fr = lane & 15, fg = lane >> 4;

    // staging coords: thread -> (row = tid/4 [+64], 16B slot = tid%4)
    const int srow = tid >> 2, slot = tid & 3;
    int ar0 = mt * 128 + srow;
    int ar1 = ar0 + 64;
    ar0 = (ar0 < rows) ? ar0 : (rows - 1);
    ar1 = (ar1 < rows) ? ar1 : (rows - 1);
    const long tok0 = tok_of_row[row0 + ar0];
    const long tok1 = tok_of_row[row0 + ar1];
    const __bf16* gA0 = xb + tok0 * D_DIM + slot * 8;
    const __bf16* gA1 = xb + tok1 * D_DIM + slot * 8;
    const __bf16* gB1a = w1b + ((long)e * F_DIM + nt * 128 + srow) * D_DIM + slot * 8;
    const __bf16* gB1b = gB1a + (long)64 * D_DIM;
    const __bf16* gB3a = w3b + ((long)e * F_DIM + nt * 128 + srow) * D_DIM + slot * 8;
    const __bf16* gB3b = gB3a + (long)64 * D_DIM;
    const int ldsoff = wave * 512;  // elements

    auto stage = [&](int buf, int t) {
        const int k0 = t * 32;
        gload16(gA0 + k0,  &As[buf][ldsoff]);
        gload16(gA1 + k0,  &As[buf][2048 + ldsoff]);
        gload16(gB1a + k0, &B1s[buf][ldsoff]);
        gload16(gB1b + k0, &B1s[buf][2048 + ldsoff]);
        gload16(gB3a + k0, &B3s[buf][ldsoff]);
        gload16(gB3b + k0, &B3s[buf][2048 + ldsoff]);
    };

    int aoff[4], boff[4];
#pragma unroll
    for (int i = 0; i < 4; ++i) {
        aoff[i] = (wm * 64 + i * 16 + fr) * 32 + fg * 8;
        boff[i] = (wn * 64 + i * 16 + fr) * 32 + fg * 8;
    }

    f32x4 accG[4][4] = {};
    f32x4 accU[4][4] = {};

    stage(0, 0);
    const int nsteps = D_DIM / 32;  // 32
    for (int t = 0; t < nsteps; ++t) {
        const int cur = t & 1;
        __syncthreads();                       // staged buf[cur] ready; prev reads drained
        if (t + 1 < nsteps) stage(cur ^ 1, t + 1);
        bf16x8 af[4], bf1[4], bf3[4];
#pragma unroll
        for (int i = 0; i < 4; ++i) {
            af[i]  = *(const bf16x8*)(&As[cur][aoff[i]]);
            bf1[i] = *(const bf16x8*)(&B1s[cur][boff[i]]);
            bf3[i] = *(const bf16x8*)(&B3s[cur][boff[i]]);
        }
#pragma unroll
        for (int mi = 0; mi < 4; ++mi)
#pragma unroll
            for (int ni = 0; ni < 4; ++ni) {
                accG[mi][ni] = __builtin_amdgcn_mfma_f32_16x16x32_bf16(af[mi], bf1[ni], accG[mi][ni], 0, 0, 0);
                accU[mi][ni] = __builtin_amdgcn_mfma_f32_16x16x32_bf16(af[mi], bf3[ni], accU[mi][ni], 0, 0, 0);
            }
    }

    // epilogue: h = silu(gate) * up, bf16.  C/D layout: n = lane&15, m = (lane>>4)*4 + r
#pragma unroll
    for (int mi = 0; mi < 4; ++mi) {
#pragma unroll
        for (int r = 0; r < 4; ++r) {
            const int lm = mt * 128 + wm * 64 + mi * 16 + fg * 4 + r;
            if (lm < rows) {
                const long hbase = (long)(row0 + lm) * F_DIM + nt * 128 + wn * 64 + fr;
#pragma unroll
                for (int ni = 0; ni < 4; ++ni) {
                    float g = accG[mi][ni][r], u = accU[mi][ni][r];
                    float s = g / (1.f + __expf(-g));
                    h[hbase + ni * 16] = (__bf16)(s * u);
                }
            }
        }
    }
}

// =========================================================================
// GEMM2: h[rows, F] x w2[e]^T [D, F] -> out[tok, d] += wgt * acc (fp32 atomic)
// =========================================================================
__global__ __launch_bounds__(256, 2)
void gemm2_kernel(const __bf16* __restrict__ h,
                  const __bf16* __restrict__ w2b,
                  const int* __restrict__ tok_of_row,
                  const float* __restrict__ wgt_of_row,
                  const int* __restrict__ offs,
                  float* __restrict__ out) {
    const int e  = blockIdx.z;
    const int mt = blockIdx.y;
    const int nt = blockIdx.x;  // over D/128 = 8
    const int row0 = offs[e];
    const int rows = offs[e + 1] - row0;
    if (mt * 128 >= rows) return;

    __shared__ __align__(16) __bf16 As[2][128 * 32];
    __shared__ __align__(16) __bf16 Bs[2][128 * 32];

    const int tid = threadIdx.x;
    const int wave = tid >> 6, lane = tid & 63;
    const int wm = wave >> 1, wn = wave & 1;
    const int fr = lane & 15, fg = lane >> 4;

    const int srow = tid >> 2, slot = tid & 3;
    int ar0 = mt * 128 + srow;
    int ar1 = ar0 + 64;
    ar0 = (ar0 < rows) ? ar0 : (rows - 1);
    ar1 = (ar1 < rows) ? ar1 : (rows - 1);
    const __bf16* gA0 = h + (long)(row0 + ar0) * F_DIM + slot * 8;
    const __bf16* gA1 = h + (long)(row0 + ar1) * F_DIM + slot * 8;
    const __bf16* gB0 = w2b + ((long)e * D_DIM + nt * 128 + srow) * F_DIM + slot * 8;
    const __bf16* gB1 = gB0 + (long)64 * F_DIM;
    const int ldsoff = wave * 512;

    auto stage = [&](int buf, int t) {
        const int k0 = t * 32;
        gload16(gA0 + k0, &As[buf][ldsoff]);
        gload16(gA1 + k0, &As[buf][2048 + ldsoff]);
        gload16(gB0 + k0, &Bs[buf][ldsoff]);
        gload16(gB1 + k0, &Bs[buf][2048 + ldsoff]);
    };

    int aoff[4], boff[4];
#pragma unroll
    for (int i = 0; i < 4; ++i) {
        aoff[i] = (wm * 64 + i * 16 + fr) * 32 + fg * 8;
        boff[i] = (wn * 64 + i * 16 + fr) * 32 + fg * 8;
    }

    f32x4 acc[4][4] = {};

    stage(0, 0);
    const int nsteps = F_DIM / 32;  // 112
    for (int t = 0; t < nsteps; ++t) {
        const int cur = t & 1;
        __syncthreads();
        if (t + 1 < nsteps) stage(cur ^ 1, t + 1);
        bf16x8 af[4], bf[4];
#pragma unroll
        for (int i = 0; i < 4; ++i) {
            af[i] = *(const bf16x8*)(&As[cur][aoff[i]]);
            bf[i] = *(const bf16x8*)(&Bs[cur][boff[i]]);
        }
#pragma unroll
        for (int mi = 0; mi < 4; ++mi)
#pragma unroll
            for (int ni = 0; ni < 4; ++ni)
                acc[mi][ni] = __builtin_amdgcn_mfma_f32_16x16x32_bf16(af[mi], bf[ni], acc[mi][ni], 0, 0, 0);
    }

#pragma unroll
    for (int mi = 0; mi < 4; ++mi) {
#pragma unroll
        for (int r = 0; r < 4; ++r) {
            const int lm = mt * 128 + wm * 64 + mi * 16 + fg * 4 + r;
            if (lm < rows) {
                const int row = row0 + lm;
                const int tok = tok_of_row[row];
                const float w = wgt_of_row[row];
                float* obase = out + (long)tok * D_DIM + nt * 128 + wn * 64 + fr;
#pragma unroll
                for (int ni = 0; ni < 4; ++ni)
                    atomicAdd(obase + ni * 16, acc[mi][ni][r] * w);
            }
        }
    }
}

// =========================================================================
extern "C" void kernel_launch(void* const* d_in, const int* in_sizes, int n_in,
                              void* d_out, int out_size, void* d_ws, size_t ws_size,
                              hipStream_t stream) {
    const float* x  = (const float*)d_in[0];
    const float* w1 = (const float*)d_in[1];
    const float* w3 = (const float*)d_in[2];
    const float* w2 = (const float*)d_in[3];
    const float* rl = (const float*)d_in[4];
    float* out = (float*)d_out;

    char* ws = (char*)d_ws;
    size_t off = 0;
    auto alloc = [&](size_t bytes) {
        void* p = ws + off;
        off += (bytes + 255) & ~(size_t)255;
        return p;
    };
    __bf16* xb  = (__bf16*)alloc((size_t)T_TOK * D_DIM * 2);
    __bf16* w1b = (__bf16*)alloc((size_t)E_EXP * F_DIM * D_DIM * 2);
    __bf16* w3b = (__bf16*)alloc((size_t)E_EXP * F_DIM * D_DIM * 2);
    __bf16* w2b = (__bf16*)alloc((size_t)E_EXP * D_DIM * F_DIM * 2);
    __bf16* h   = (__bf16*)alloc((size_t)NROW * F_DIM * 2);
    int*   tok  = (int*)alloc(NROW * 4);
    float* wgt  = (float*)alloc(NROW * 4);
    int*   eidx = (int*)alloc(NROW * 4);
    float* ewgt = (float*)alloc(NROW * 4);
    int*   cnt1 = (int*)alloc(64);
    int*   cnt2 = (int*)alloc(64);
    int*   offs = (int*)alloc(64);

    hipMemsetAsync(d_out, 0, (size_t)out_size * 4, stream);
    hipMemsetAsync(cnt1, 0, 64, stream);
    hipMemsetAsync(cnt2, 0, 64, stream);

    // fp32 -> bf16
    {
        long n = (long)T_TOK * D_DIM;
        cvt_kernel<<<(int)(n / 4 / 256), 256, 0, stream>>>(x, xb, n);
        n = (long)E_EXP * F_DIM * D_DIM;
        int blks = (int)(n / 4 / 256);
        cvt_kernel<<<blks, 256, 0, stream>>>(w1, w1b, n);
        cvt_kernel<<<blks, 256, 0, stream>>>(w3, w3b, n);
        cvt_kernel<<<blks, 256, 0, stream>>>(w2, w2b, n);
    }

    route_kernel<<<T_TOK / 256, 256, 0, stream>>>(rl, cnt1, eidx, ewgt);
    scan_kernel<<<1, 64, 0, stream>>>(cnt1, offs);
    assign_kernel<<<T_TOK / 256, 256, 0, stream>>>(eidx, ewgt, offs, cnt2, tok, wgt);

    dim3 g1(F_DIM / 128, T_TOK / 128, E_EXP);   // (28, 64, 8); most m-tiles early-exit
    gemm1_kernel<<<g1, 256, 0, stream>>>(xb, w1b, w3b, tok, offs, h);

    dim3 g2(D_DIM / 128, T_TOK / 128, E_EXP);   // (8, 64, 8)
    gemm2_kernel<<<g2, 256, 0, stream>>>(h, w2b, tok, wgt, offs, out);
}